// Round 1
// baseline (67.923 us; speedup 1.0000x reference)
//
#include <hip/hip_runtime.h>
#include <math.h>

// Problem constants (from reference)
#define B_     4
#define N_     1024
#define L_     150
#define VOCAB_ 5
#define EMB_   128
#define UNITS_ 64

// Reference takes outs[0] == hidden state after the FIRST LSTM step with
// h0=c0=0:
//   z  = emb_table[tok0] @ kernel + bias   (rec_kernel term vanishes)
//   c1 = sigmoid(z_i) * tanh(z_g)          (f*c0 vanishes)
//   h1 = sigmoid(z_o) * tanh(c1)
// Only tokens[:, :, 0] matters; vocab=5 -> only 5 distinct output rows.
//
// R2: split into two kernels through d_ws.
//  - Kernel A: ONE block (320 threads) computes the 5x64 h-table once
//    (previously all 205 blocks recomputed it redundantly: ~100 MB of
//    L1/L2 kern traffic + 128-deep FMA chains at 1 wave/SIMD, serialized
//    ahead of the writes by __syncthreads).
//  - Kernel B: pure streaming gather: 65536 float4 outputs, one per
//    thread, table is 5 KB (L1/L2 resident), tokens read once per row.

__global__ __launch_bounds__(320) void build_table_kernel(
    const float* __restrict__ emb,     // [VOCAB, EMB]
    const float* __restrict__ kern,    // [EMB, 4*UNITS] gate order i,f,g,o
    const float* __restrict__ bias,    // [4*UNITS]
    float*       __restrict__ table)   // [VOCAB*UNITS] in workspace
{
    const int tid = threadIdx.x;       // 0..319, one (v,u) per thread
    const int v = tid >> 6;            // wave index == vocab id (wave-uniform)
    const int u = tid & 63;

    float zi = bias[u];
    float zg = bias[2 * UNITS_ + u];
    float zo = bias[3 * UNITS_ + u];

    const float4* ev4 = (const float4*)(emb + v * EMB_);
    const float*  kc  = kern + u;   // column base; rows stride 4*UNITS_

    #pragma unroll 8
    for (int e4 = 0; e4 < EMB_ / 4; ++e4) {
        const float4 a = ev4[e4];   // wave-broadcast load
        const float* k0 = kc + (4 * e4) * (4 * UNITS_);
        zi = fmaf(a.x, k0[0 * 256],              zi);
        zg = fmaf(a.x, k0[0 * 256 + 2 * UNITS_], zg);
        zo = fmaf(a.x, k0[0 * 256 + 3 * UNITS_], zo);
        zi = fmaf(a.y, k0[1 * 256],              zi);
        zg = fmaf(a.y, k0[1 * 256 + 2 * UNITS_], zg);
        zo = fmaf(a.y, k0[1 * 256 + 3 * UNITS_], zo);
        zi = fmaf(a.z, k0[2 * 256],              zi);
        zg = fmaf(a.z, k0[2 * 256 + 2 * UNITS_], zg);
        zo = fmaf(a.z, k0[2 * 256 + 3 * UNITS_], zo);
        zi = fmaf(a.w, k0[3 * 256],              zi);
        zg = fmaf(a.w, k0[3 * 256 + 2 * UNITS_], zg);
        zo = fmaf(a.w, k0[3 * 256 + 3 * UNITS_], zo);
    }

    const float ig = 1.0f / (1.0f + expf(-zi));
    const float g  = tanhf(zg);
    const float og = 1.0f / (1.0f + expf(-zo));
    table[tid] = og * tanhf(ig * g);
}

// 65536 float4 outputs, 256 blocks x 256 threads = exact cover.
#define GBLOCK_ 256
#define GGRID_  256

__global__ __launch_bounds__(GBLOCK_) void gather_kernel(
    const int*    __restrict__ tokens,  // [B, N, L]
    const float4* __restrict__ table4,  // [VOCAB*UNITS/4] in workspace
    float4*       __restrict__ out4)    // [B*N*UNITS/4]
{
    const int i   = blockIdx.x * GBLOCK_ + threadIdx.x;  // 0..65535
    const int row = i >> 4;   // / (UNITS_/4)
    const int seg = i & 15;   // % (UNITS_/4)
    const int tok = tokens[row * L_];  // broadcast within 16-thread groups
    out4[i] = table4[tok * (UNITS_ / 4) + seg];
}

extern "C" void kernel_launch(void* const* d_in, const int* in_sizes, int n_in,
                              void* d_out, int out_size, void* d_ws, size_t ws_size,
                              hipStream_t stream) {
    const int*   tokens = (const int*)d_in[0];    // [4,1024,150] int32
    const float* emb    = (const float*)d_in[1];  // [5,128]
    const float* kern   = (const float*)d_in[2];  // [128,256]
    // d_in[3] = rec_kernel [64,256] -- unused (h0 = 0)
    const float* bias   = (const float*)d_in[4];  // [256]
    float* out   = (float*)d_out;                 // [4,1024,1,64] fp32
    float* table = (float*)d_ws;                  // 5*64 floats = 1.25 KB

    build_table_kernel<<<1, 320, 0, stream>>>(emb, kern, bias, table);
    gather_kernel<<<GGRID_, GBLOCK_, 0, stream>>>(tokens, (const float4*)table,
                                                  (float4*)out);
}